// Round 2
// baseline (725.992 us; speedup 1.0000x reference)
//
#include <hip/hip_runtime.h>

// out[16384,16] = x[16384,8192] @ W[8192,16], all fp32. Memory-bound: x = 512 MiB
// dominates -> HBM floor ~86 us at 6.3 TB/s achievable.
//
// R2 changes vs R1 (695 us):
//  - RPW 8->4: acc = 64 VGPRs; ~120 total, fits 128-cap => 4 blocks/CU, 16 waves/CU
//  - no pointer casts on local arrays (they can defeat SROA -> scratch); all
//    float4 component access is compile-time .x/.y/.z/.w selection
//  - grid 1024 x 256 threads, __launch_bounds__(256,4)
// W staged through LDS in 16KB K-tiles, double-buffered, XOR-swizzled so both
// the cooperative ds_write_b128 and the per-lane row ds_read_b128 hit all 8
// bank groups (structural minimum, zero extra conflicts).

#define BATCH      16384
#define K_DIM      8192
#define OUT_DIM    16
#define KT         256                  // k's per LDS tile
#define NT         (K_DIM / KT)         // 32 tiles
#define RPW        4                    // rows per wave
#define RPB        16                   // rows per block (4 waves * 4)

__global__ __launch_bounds__(256, 4)
void NN_48696339202344_kernel(const float* __restrict__ x,
                              const float* __restrict__ W,
                              float* __restrict__ out) {
    // 2 buffers * 1024 float4 chunks * 16B = 32 KB
    __shared__ float4 lds[2 * 1024];

    const int u    = threadIdx.x;   // 0..255
    const int wave = u >> 6;        // 0..3
    const int lane = u & 63;        // 0..63
    const int rb   = blockIdx.x * RPB + wave * RPW;  // this wave's first row

    const float4* __restrict__ Wv = (const float4*)W;   // 32768 16B chunks

    float acc[RPW][OUT_DIM];
    #pragma unroll
    for (int r = 0; r < RPW; ++r)
        #pragma unroll
        for (int o = 0; o < OUT_DIM; ++o) acc[r][o] = 0.f;

    // x base (lane offset folded in); row r at +r*K_DIM
    const float* xb = x + (size_t)rb * K_DIM + 4 * lane;

    // ---- prologue: stage W tile 0 into buffer 0 ----
    {
        float4 s0 = Wv[0 * 256 + u];
        float4 s1 = Wv[1 * 256 + u];
        float4 s2 = Wv[2 * 256 + u];
        float4 s3 = Wv[3 * 256 + u];
        #pragma unroll
        for (int q = 0; q < 4; ++q) {
            const int m   = q * 256 + u;
            const int pos = m ^ ((m >> 4) & 7);
            lds[pos] = (q == 0) ? s0 : (q == 1) ? s1 : (q == 2) ? s2 : s3;
        }
    }
    __syncthreads();

    for (int i = 0; i < NT; ++i) {
        const int cur  = (i & 1) * 1024;
        const int k0   = i * KT;
        const bool pre = (i + 1 < NT);

        // prefetch next W tile into regs (overlaps this tile's compute)
        float4 s0, s1, s2, s3;
        if (pre) {
            const int tb = (i + 1) * 1024;
            s0 = Wv[tb + 0 * 256 + u];
            s1 = Wv[tb + 1 * 256 + u];
            s2 = Wv[tb + 2 * 256 + u];
            s3 = Wv[tb + 3 * 256 + u];
        }

        // x: one float4 per row (64 lanes * 16B contiguous = coalesced 1KB)
        float4 xv[RPW];
        #pragma unroll
        for (int r = 0; r < RPW; ++r)
            xv[r] = *(const float4*)(xb + r * K_DIM + k0);

        // compute: this lane's k = k0 + 4*lane + j
        #pragma unroll
        for (int j = 0; j < 4; ++j) {
            float xs[RPW];
            #pragma unroll
            for (int r = 0; r < RPW; ++r)
                xs[r] = (j == 0) ? xv[r].x : (j == 1) ? xv[r].y
                      : (j == 2) ? xv[r].z : xv[r].w;
            const int mb = 16 * lane + 4 * j;
            #pragma unroll
            for (int c = 0; c < 4; ++c) {
                const int m   = mb + c;
                const int pos = (m ^ (lane & 7)) + cur;   // (m>>4)&7 == lane&7 here
                const float4 wc = lds[pos];
                #pragma unroll
                for (int r = 0; r < RPW; ++r) {
                    acc[r][4 * c + 0] = fmaf(xs[r], wc.x, acc[r][4 * c + 0]);
                    acc[r][4 * c + 1] = fmaf(xs[r], wc.y, acc[r][4 * c + 1]);
                    acc[r][4 * c + 2] = fmaf(xs[r], wc.z, acc[r][4 * c + 2]);
                    acc[r][4 * c + 3] = fmaf(xs[r], wc.w, acc[r][4 * c + 3]);
                }
            }
        }

        // write prefetched W tile into the other buffer
        if (pre) {
            const int nxt = (cur ^ 1024);
            #pragma unroll
            for (int q = 0; q < 4; ++q) {
                const int m   = q * 256 + u;
                const int pos = (m ^ ((m >> 4) & 7)) + nxt;
                lds[pos] = (q == 0) ? s0 : (q == 1) ? s1 : (q == 2) ? s2 : s3;
            }
        }
        __syncthreads();
    }

    // ---- epilogue: wave holds 4 rows x 16 outs = 64 values; bisection reduce
    // leaves lane l with the total of value l (row l/16, col l%16); one
    // coalesced 256B store per wave.
    float vals[64];
    #pragma unroll
    for (int r = 0; r < RPW; ++r)
        #pragma unroll
        for (int o = 0; o < OUT_DIM; ++o)
            vals[r * 16 + o] = acc[r][o];

    #pragma unroll
    for (int d = 32; d >= 1; d >>= 1) {
        const bool hi = (lane & d) != 0;
        #pragma unroll
        for (int idx = 0; idx < d; ++idx) {
            const float keep = hi ? vals[idx + d] : vals[idx];
            const float send = hi ? vals[idx]     : vals[idx + d];
            const float recv = __shfl_xor(send, d, 64);
            vals[idx] = keep + recv;
        }
    }
    out[(size_t)rb * OUT_DIM + lane] = vals[0];
}

extern "C" void kernel_launch(void* const* d_in, const int* in_sizes, int n_in,
                              void* d_out, int out_size, void* d_ws, size_t ws_size,
                              hipStream_t stream) {
    const float* x = (const float*)d_in[0];
    const float* W = (const float*)d_in[1];
    float* out     = (float*)d_out;
    dim3 grid(BATCH / RPB);   // 1024 blocks
    dim3 block(256);
    NN_48696339202344_kernel<<<grid, block, 0, stream>>>(x, W, out);
}